// Round 5
// baseline (75.712 us; speedup 1.0000x reference)
//
#include <hip/hip_runtime.h>
#include <math.h>

// VanillaSFNN: B=1024, T=1024, H=256, IN=2, OUT=2, DECAY=0.8
// Round 5: R4 structure + prefetch distance 4 LDS entries (8 steps) via a
// 4-register float4 ring, explicit 4-body unroll (zero-mov rotation).
// Rationale: 4 waves/SIMD leave the barrier in lockstep; with distance-2 the
// periodic ds_read stall (~120cy) hits all waves at once (13% VALU idle).
// Distance-4 puts ~700 wall-cy between load and use.
// Per-step math identical to R1/R4 (bit-exact vs numpy reference, 11 VALU ops).

constexpr int T_STEPS = 1024;
constexpr int HIDDEN  = 256;
constexpr int NENT    = T_STEPS / 2;   // 512 float4 LDS entries, 2 steps each

__global__ __launch_bounds__(256) void sfnn_sc_kernel(
    const float* __restrict__ x_seq,   // [B, T, 2]
    const float* __restrict__ W_in,    // [H, 2]
    const float* __restrict__ b_in,    // [H]
    const float* __restrict__ W_out,   // [2, H]
    const float* __restrict__ b_out,   // [2]
    const float* __restrict__ tau_m,   // [H]
    float* __restrict__ out)           // [B, 2]
{
    __shared__ float4 xs[NENT];        // 8 KB: x[b]
    __shared__ float  red[8];          // cross-wave epilogue partials

    const int b   = blockIdx.x;
    const int tid = threadIdx.x;

    // --- stage x[b] into LDS (coalesced float4) ---
    const float4* __restrict__ xg =
        reinterpret_cast<const float4*>(x_seq) + (size_t)b * NENT;
    xs[tid]          = xg[tid];
    xs[tid + HIDDEN] = xg[tid + HIDDEN];

    // --- per-hidden constants ---
    const float w0  = W_in[2 * tid];
    const float w1  = W_in[2 * tid + 1];
    const float bi  = b_in[tid];
    const float al  = 1.0f / (1.0f + expf(-tau_m[tid]));
    const float be  = 1.0f - al;

    __syncthreads();

    float v = 0.0f;
    float S = 0.0f;

    // one LIF step; arithmetic order matches the reference exactly (11 VALU)
    #define LIF_STEP(X0, X1)                                                  \
        {                                                                     \
            float cur = __fadd_rn(__fadd_rn(__fmul_rn((X0), w0),              \
                                            __fmul_rn((X1), w1)), bi);        \
            v = __fadd_rn(__fmul_rn(v, al), __fmul_rn(be, cur));              \
            float sp = (v >= 1.0f) ? 1.0f : 0.0f;                             \
            v -= sp;                                                          \
            S = fmaf(0.8f, S, sp);                                            \
        }
    #define LIF2(R) LIF_STEP((R).x, (R).y) LIF_STEP((R).z, (R).w)

    // --- main loop: 4-entry ring, prefetch distance 4 (8 steps) ---
    float4 r0 = xs[0];
    float4 r1 = xs[1];
    float4 r2 = xs[2];
    float4 r3 = xs[3];
    for (int i = 0; i < NENT - 4; i += 4) {
        LIF2(r0) r0 = xs[i + 4];
        LIF2(r1) r1 = xs[i + 5];
        LIF2(r2) r2 = xs[i + 6];
        LIF2(r3) r3 = xs[i + 7];
    }
    LIF2(r0) LIF2(r1) LIF2(r2) LIF2(r3)
    #undef LIF2
    #undef LIF_STEP

    // --- epilogue: project S onto W_out, wave shuffle-reduce, combine ---
    float r0s = S * W_out[tid];
    float r1s = S * W_out[HIDDEN + tid];
    #pragma unroll
    for (int off = 32; off > 0; off >>= 1) {
        r0s += __shfl_xor(r0s, off, 64);
        r1s += __shfl_xor(r1s, off, 64);
    }
    const int wave = tid >> 6;
    if ((tid & 63) == 0) {
        red[2 * wave]     = r0s;
        red[2 * wave + 1] = r1s;
    }
    __syncthreads();
    if (tid == 0) {
        const float geo = 5.0f;   // sum_{k=0}^{1023} 0.8^k rounds to 5.0f
        float o0 = (red[0] + red[2]) + (red[4] + red[6]);
        float o1 = (red[1] + red[3]) + (red[5] + red[7]);
        out[2 * b]     = o0 + b_out[0] * geo;
        out[2 * b + 1] = o1 + b_out[1] * geo;
    }
}

extern "C" void kernel_launch(void* const* d_in, const int* in_sizes, int n_in,
                              void* d_out, int out_size, void* d_ws, size_t ws_size,
                              hipStream_t stream) {
    const float* x_seq = (const float*)d_in[0];
    const float* W_in  = (const float*)d_in[1];
    const float* b_in  = (const float*)d_in[2];
    const float* W_out = (const float*)d_in[3];
    const float* b_out = (const float*)d_in[4];
    const float* tau_m = (const float*)d_in[5];
    float* out = (float*)d_out;

    sfnn_sc_kernel<<<dim3(1024), dim3(256), 0, stream>>>(
        x_seq, W_in, b_in, W_out, b_out, tau_m, out);
}

// Round 7
// 62.429 us; speedup vs baseline: 1.2128x; 1.2128x over previous
//
#include <hip/hip_runtime.h>
#include <math.h>

// VanillaSFNN: B=1024, T=1024, H=256, IN=2, OUT=2, DECAY=0.8
// Round 7 (= R6 with compile fix: ext_vector_type instead of struct float4
// for the ring registers so __builtin_shufflevector works).
// Packed f32 (v_pk full-rate per R2/R3 busy-time accounting) + stall fixes:
//   - block=128, grid=1024 (2 waves/SIMD); lane handles h=tid and h=tid+128
//   - plain {x0,x1} LDS layout (8KB, conflict-free), op_sel broadcasts the
//     shared x scalar to both packed halves (bit-exact-proven in R3)
//   - register ring prefetch distance 4 entries (8 steps)
//   - 8-step unrolled body: 4 independent cur-chains hide v-chain latency
// Per-half arithmetic identical to reference f32 op order -> absmax 0.

constexpr int T_STEPS = 1024;
constexpr int HIDDEN  = 256;
constexpr int BLK     = 128;
constexpr int NENT    = T_STEPS / 2;   // 512 entries, 2 steps each

typedef float f32x2 __attribute__((ext_vector_type(2)));
typedef float f32x4 __attribute__((ext_vector_type(4)));

static __device__ __forceinline__ f32x2 pk_mul(f32x2 a, f32x2 b) {
    f32x2 d; asm("v_pk_mul_f32 %0, %1, %2" : "=v"(d) : "v"(a), "v"(b)); return d;
}
static __device__ __forceinline__ f32x2 pk_add(f32x2 a, f32x2 b) {
    f32x2 d; asm("v_pk_add_f32 %0, %1, %2" : "=v"(d) : "v"(a), "v"(b)); return d;
}
static __device__ __forceinline__ f32x2 pk_fma(f32x2 a, f32x2 b, f32x2 c) {
    f32x2 d; asm("v_pk_fma_f32 %0, %1, %2, %3" : "=v"(d) : "v"(a), "v"(b), "v"(c)); return d;
}
// lo = x.lo*w.lo, hi = x.lo*w.hi  (broadcast word0 of x)
static __device__ __forceinline__ f32x2 pk_mul_bc0(f32x2 x, f32x2 w) {
    f32x2 d; asm("v_pk_mul_f32 %0, %1, %2 op_sel:[0,0] op_sel_hi:[0,1]"
                 : "=v"(d) : "v"(x), "v"(w)); return d;
}
// lo = x.hi*w.lo, hi = x.hi*w.hi  (broadcast word1 of x)
static __device__ __forceinline__ f32x2 pk_mul_bc1(f32x2 x, f32x2 w) {
    f32x2 d; asm("v_pk_mul_f32 %0, %1, %2 op_sel:[1,0] op_sel_hi:[1,1]"
                 : "=v"(d) : "v"(x), "v"(w)); return d;
}

__global__ __launch_bounds__(BLK) void sfnn_pk2_kernel(
    const float* __restrict__ x_seq,   // [B, T, 2]
    const float* __restrict__ W_in,    // [H, 2]
    const float* __restrict__ b_in,    // [H]
    const float* __restrict__ W_out,   // [2, H]
    const float* __restrict__ b_out,   // [2]
    const float* __restrict__ tau_m,   // [H]
    float* __restrict__ out)           // [B, 2]
{
    __shared__ f32x4 xs[NENT];         // 8 KB: plain x[b]
    __shared__ float red[4];           // cross-wave epilogue partials

    const int b   = blockIdx.x;
    const int tid = threadIdx.x;
    const int h0  = tid;
    const int h1  = tid + BLK;

    // --- stage x[b] into LDS (coalesced 16B, conflict-free) ---
    const f32x4* __restrict__ xg =
        reinterpret_cast<const f32x4*>(x_seq) + (size_t)b * NENT;
    #pragma unroll
    for (int k = 0; k < NENT / BLK; ++k)
        xs[tid + k * BLK] = xg[tid + k * BLK];

    // --- per-lane packed constants ---
    f32x2 w0p, w1p, bip, alp, bep, c08;
    w0p.x = W_in[2 * h0];     w0p.y = W_in[2 * h1];
    w1p.x = W_in[2 * h0 + 1]; w1p.y = W_in[2 * h1 + 1];
    bip.x = b_in[h0];         bip.y = b_in[h1];
    alp.x = 1.0f / (1.0f + expf(-tau_m[h0]));
    alp.y = 1.0f / (1.0f + expf(-tau_m[h1]));
    bep.x = 1.0f - alp.x;     bep.y = 1.0f - alp.y;
    c08.x = 0.8f;             c08.y = 0.8f;

    __syncthreads();

    f32x2 v  = {0.0f, 0.0f};
    f32x2 Sn = {0.0f, 0.0f};           // negated decayed spike sum

    // one LIF step for both h-units; xp = {x0(t), x1(t)}
    #define LIF_STEP(XP)                                                      \
        {                                                                     \
            f32x2 cur = pk_add(pk_add(pk_mul_bc0((XP), w0p),                  \
                                      pk_mul_bc1((XP), w1p)), bip);           \
            v = pk_add(pk_mul(v, alp), pk_mul(bep, cur));                     \
            f32x2 spn;                                                        \
            spn.x = (v.x >= 1.0f) ? -1.0f : 0.0f;                             \
            spn.y = (v.y >= 1.0f) ? -1.0f : 0.0f;                             \
            v  = pk_add(v, spn);                                              \
            Sn = pk_fma(c08, Sn, spn);                                        \
        }
    #define LIF2(Q)                                                           \
        LIF_STEP(__builtin_shufflevector((Q), (Q), 0, 1))                     \
        LIF_STEP(__builtin_shufflevector((Q), (Q), 2, 3))

    // --- main loop: 4-entry register ring (prefetch distance 4 = 8 steps) ---
    f32x4 q0 = xs[0];
    f32x4 q1 = xs[1];
    f32x4 q2 = xs[2];
    f32x4 q3 = xs[3];
    for (int i = 0; i < NENT - 4; i += 4) {
        LIF2(q0) q0 = xs[i + 4];
        LIF2(q1) q1 = xs[i + 5];
        LIF2(q2) q2 = xs[i + 6];
        LIF2(q3) q3 = xs[i + 7];
    }
    LIF2(q0) LIF2(q1) LIF2(q2) LIF2(q3)
    #undef LIF2
    #undef LIF_STEP

    // --- epilogue: project -Sn onto W_out, wave shuffle-reduce, combine ---
    const float Sx = -Sn.x, Sy = -Sn.y;
    float r0 = fmaf(Sy, W_out[h1],          Sx * W_out[h0]);
    float r1 = fmaf(Sy, W_out[HIDDEN + h1], Sx * W_out[HIDDEN + h0]);
    #pragma unroll
    for (int off = 32; off > 0; off >>= 1) {
        r0 += __shfl_xor(r0, off, 64);
        r1 += __shfl_xor(r1, off, 64);
    }
    const int wave = tid >> 6;
    if ((tid & 63) == 0) {
        red[2 * wave]     = r0;
        red[2 * wave + 1] = r1;
    }
    __syncthreads();
    if (tid == 0) {
        const float geo = 5.0f;   // sum_{k=0}^{1023} 0.8^k rounds to 5.0f
        out[2 * b]     = (red[0] + red[2]) + b_out[0] * geo;
        out[2 * b + 1] = (red[1] + red[3]) + b_out[1] * geo;
    }
}

extern "C" void kernel_launch(void* const* d_in, const int* in_sizes, int n_in,
                              void* d_out, int out_size, void* d_ws, size_t ws_size,
                              hipStream_t stream) {
    const float* x_seq = (const float*)d_in[0];
    const float* W_in  = (const float*)d_in[1];
    const float* b_in  = (const float*)d_in[2];
    const float* W_out = (const float*)d_in[3];
    const float* b_out = (const float*)d_in[4];
    const float* tau_m = (const float*)d_in[5];
    float* out = (float*)d_out;

    sfnn_pk2_kernel<<<dim3(1024), dim3(BLK), 0, stream>>>(
        x_seq, W_in, b_in, W_out, b_out, tau_m, out);
}